// Round 8
// baseline (102.268 us; speedup 1.0000x reference)
//
#include <hip/hip_runtime.h>
#include <hip/hip_bf16.h>

#define B_SZ 4096
#define F_N  39
#define V_N  100000
#define D_N  16
#define H_N  400
#define K1   624      // F*D
#define K1P  640      // K1 padded
#define NP   512      // H padded

typedef __attribute__((ext_vector_type(8))) short short8;
typedef __attribute__((ext_vector_type(4))) float f32x4;
typedef const __attribute__((address_space(1))) void g_void;
typedef __attribute__((address_space(3))) void l_void;

// ---------------- prep: W[k][n] fp32 -> Wt_swz[n][k] bf16, chunk-XOR --------
// global layout: chunk index c (8 bf16 = 16B) stored at c' = c XOR-low3 (n&7).
// mega stages linearly via global_load_lds and applies the XOR on ds_read.
#define W1_TILES 80   // (640/64) x (512/64)
#define W2_TILES 64   // 8 x 8
__global__ __launch_bounds__(256) void prep_kernel(
    const float* __restrict__ W1, const float* __restrict__ W2,
    __hip_bfloat16* __restrict__ W1s, __hip_bfloat16* __restrict__ W2s)
{
    __shared__ float tile[64 * 65];   // [n_local][k_local]
    const int tid = threadIdx.x;
    int tb = blockIdx.x;

    const float* Wsrc; __hip_bfloat16* Wdst;
    int Ksrc, Kdst, kb, nb;
    if (tb < W1_TILES) { Wsrc = W1; Wdst = W1s; Ksrc = K1;  Kdst = K1P; kb = tb >> 3; nb = tb & 7; }
    else { tb -= W1_TILES; Wsrc = W2; Wdst = W2s; Ksrc = H_N; Kdst = NP; kb = tb >> 3; nb = tb & 7; }
    const int k0 = kb * 64, n0 = nb * 64;

    #pragma unroll
    for (int p = 0; p < 4; ++p) {
        const int r  = (tid >> 4) + p * 16;   // src row (k)
        const int c4 = (tid & 15) * 4;        // src col (n)
        const int gk = k0 + r, gn = n0 + c4;
        float4 v = make_float4(0.f, 0.f, 0.f, 0.f);
        if (gk < Ksrc && gn + 3 < H_N)
            v = *(const float4*)(Wsrc + (size_t)gk * H_N + gn);
        tile[(c4 + 0) * 65 + r] = v.x;
        tile[(c4 + 1) * 65 + r] = v.y;
        tile[(c4 + 2) * 65 + r] = v.z;
        tile[(c4 + 3) * 65 + r] = v.w;
    }
    __syncthreads();

    const int rr = tid >> 2;            // n_local
    const int cc = (tid & 3) * 16;      // k_local
    const int n  = n0 + rr;
    short8 s0, s1;
    #pragma unroll
    for (int j = 0; j < 8; ++j) {
        s0[j] = (short)__bfloat16_as_ushort(__float2bfloat16(tile[rr * 65 + cc + j]));
        s1[j] = (short)__bfloat16_as_ushort(__float2bfloat16(tile[rr * 65 + cc + 8 + j]));
    }
    const int c0  = (k0 + cc) >> 3;
    const int c1  = c0 + 1;
    const int c0s = (c0 & ~7) | ((c0 ^ n) & 7);
    const int c1s = (c1 & ~7) | ((c1 ^ n) & 7);
    *(short8*)(Wdst + (size_t)n * Kdst + c0s * 8) = s0;
    *(short8*)(Wdst + (size_t)n * Kdst + c1s * 8) = s1;
}

// ---------------- mega: 16 rows/block end-to-end, no cross-block deps -------
// LDS offsets (bytes)
#define BS_OFF   0          // 3 x [64n][128k] bf16 staging bufs = 49152
#define A1_OFF   49152      // [16][640] bf16 swz = 20480
#define H_OFF    69632      // [16][512] bf16 swz = 16384
#define S32_OFF  86016      // [16][624] f32     = 39936
#define SIDX_OFF 125952     // 624 int
#define SVAL_OFF 128448     // 624 f32
#define FM_OFF   130944     // 16 f32
#define DP_OFF   131008     // 64 f32
#define SH_BYTES 131264

#define NSTG 72             // GEMM1: 8nt x 5kt = 40 ; GEMM2: 8nt x 4kt = 32

__global__ __launch_bounds__(256) void mega_kernel(
    const int*   __restrict__ Xi,
    const float* __restrict__ Xv,
    const float* __restrict__ fst_t,
    const float* __restrict__ sec_t,
    const float* __restrict__ bias,
    const float* __restrict__ b1,
    const float* __restrict__ b2,
    const __hip_bfloat16* __restrict__ W1s,
    const __hip_bfloat16* __restrict__ W2s,
    float* __restrict__ out)
{
    __shared__ __align__(16) char sh[SH_BYTES];

    const int bid  = blockIdx.x;
    const int tid  = threadIdx.x;
    const int lane = tid & 63;
    const int w    = tid >> 6;      // wave 0..3 (n-split: 16 cols each per tile)
    const int lr   = lane & 15;
    const int lg4  = lane >> 4;

    const float bias0 = bias[0];

    int*   sidx = (int*)(sh + SIDX_OFF);
    float* sval = (float*)(sh + SVAL_OFF);

    // ---------- gather: 16 rows, sec -> sec32 (fp32) + A1 (bf16, swz) -------
    {
        #pragma unroll
        for (int j = 0; j < 3; ++j) {
            const int idx = tid + j * 256;
            if (idx < 16 * F_N) {
                sidx[idx] = Xi[bid * (16 * F_N) + idx];
                sval[idx] = Xv[bid * (16 * F_N) + idx];
            }
        }
        __syncthreads();

        const int r = tid >> 4;                 // row 0..15
        float4 gv[10];
        #pragma unroll
        for (int p = 0; p < 10; ++p) {
            const int sl = p * 16 + (tid & 15); // slot 0..159
            if (sl < 156) {
                const int f = sl >> 2, q = sl & 3;
                gv[p] = *(const float4*)(sec_t +
                        ((long long)f * V_N + sidx[r * F_N + f]) * D_N + q * 4);
            } else {
                gv[p] = make_float4(0.f, 0.f, 0.f, 0.f);
            }
        }
        #pragma unroll
        for (int p = 0; p < 10; ++p) {
            const int sl = p * 16 + (tid & 15);
            float4 v = gv[p];
            if (sl < 156) {
                const float val = sval[r * F_N + (sl >> 2)];
                v.x *= val; v.y *= val; v.z *= val; v.w *= val;
                *(float4*)(sh + S32_OFF + r * 2496 + sl * 16) = v;
            }
            ushort4 pk;
            pk.x = __bfloat16_as_ushort(__float2bfloat16(v.x));
            pk.y = __bfloat16_as_ushort(__float2bfloat16(v.y));
            pk.z = __bfloat16_as_ushort(__float2bfloat16(v.z));
            pk.w = __bfloat16_as_ushort(__float2bfloat16(v.w));
            // A1 swz: chunk (sl>>1) ^ (r&7), 8B half-chunk (sl&1)
            *(ushort4*)(sh + A1_OFF + r * 1280 +
                        (((sl >> 1) ^ (r & 7)) << 4) + (sl & 1) * 8) = pk;
        }
        __syncthreads();
    }

    // ---------- FM + fst (fp32 exact) --------------------------------------
    {
        const int r = tid >> 4, d = tid & 15;
        float part = 0.f;
        #pragma unroll
        for (int f = 0; f < 3; ++f) {
            const int ff = d + f * 16;
            if (ff < F_N)
                part += fst_t[(long long)ff * V_N + sidx[r * F_N + ff]] * sval[r * F_N + ff];
        }
        float ssq = 0.f;
        #pragma unroll
        for (int i = 0; i < 39; ++i) {
            const float v = *(const float*)(sh + S32_OFF + r * 2496 + (i * 16 + d) * 4);
            ssq += v * v;
        }
        float sd = 0.f;
        #pragma unroll
        for (int f = 0; f < F_N; ++f)
            sd += *(const float*)(sh + S32_OFF + r * 2496 + (f * 16 + d) * 4);
        part += 0.5f * (sd * sd) - 0.5f * ssq;
        #pragma unroll
        for (int off = 1; off < 16; off <<= 1) part += __shfl_xor(part, off, 64);
        if (d == 0) *(float*)(sh + FM_OFF + r * 4) = part + bias0;
    }

    // ---------- preload biases (per-wave col slices) + A1 fragments ---------
    float b1v[8], b2v[8];
    #pragma unroll
    for (int nt = 0; nt < 8; ++nt) {
        const int col = nt * 64 + w * 16 + lr;
        b1v[nt] = (col < H_N) ? b1[col] : 0.f;
        b2v[nt] = (col < H_N) ? b2[col] : 0.f;
    }
    short8 a1[20];
    #pragma unroll
    for (int kt = 0; kt < 20; ++kt)
        a1[kt] = *(const short8*)(sh + A1_OFF + lr * 1280 +
                                  (((kt * 4 + lg4) ^ (lr & 7)) << 4));

    // ---------- staged GEMM pipeline: counted vmcnt, 3 bufs -----------------
    auto STAGE = [&](int buf, int s) {
        const __hip_bfloat16* src; int n0, k0, ld;
        if (s < 40) { src = W1s; n0 = (s / 5) * 64; k0 = (s % 5) * 128; ld = K1P; }
        else { const int q = s - 40; src = W2s; n0 = (q / 4) * 64; k0 = (q % 4) * 128; ld = NP; }
        #pragma unroll
        for (int i = 0; i < 4; ++i) {
            const int nloc = (tid >> 4) + i * 16;
            __builtin_amdgcn_global_load_lds(
                (g_void*)(src + (size_t)(n0 + nloc) * ld + k0 + (tid & 15) * 8),
                (l_void*)(sh + BS_OFF + buf * 16384 + nloc * 256 + (tid & 15) * 16),
                16, 0, 0);
        }
    };

    asm volatile("s_waitcnt vmcnt(0)" ::: "memory");   // drain gather/bias loads
    STAGE(0, 0);
    STAGE(1, 1);

    f32x4 acc = {0.f, 0.f, 0.f, 0.f};
    float rowacc[4] = {0.f, 0.f, 0.f, 0.f};
    short8 a2[16];
    const int nx = lr & 7;

    #pragma unroll
    for (int s = 0; s < NSTG; ++s) {
        if (s + 1 < NSTG) asm volatile("s_waitcnt vmcnt(4) lgkmcnt(0)" ::: "memory");
        else              asm volatile("s_waitcnt vmcnt(0) lgkmcnt(0)" ::: "memory");
        __builtin_amdgcn_s_barrier();

        if (s == 40) {   // h complete & published: preload GEMM2 A fragments
            #pragma unroll
            for (int kt = 0; kt < 16; ++kt)
                a2[kt] = *(const short8*)(sh + H_OFF + lr * 1024 +
                                          (((kt * 4 + lg4) ^ (lr & 7)) << 4));
        }
        if (s + 2 < NSTG) STAGE((s + 2) % 3, s + 2);

        const char* bsb = sh + BS_OFF + (s % 3) * 16384 + (w * 16 + lr) * 256;
        if (s < 40) {
            const int kt = s % 5;
            #pragma unroll
            for (int kk = 0; kk < 4; ++kk) {
                const short8 bb = *(const short8*)(bsb + (((kk * 4 + lg4) ^ nx) << 4));
                acc = __builtin_amdgcn_mfma_f32_16x16x32_bf16(a1[kt * 4 + kk], bb, acc, 0, 0, 0);
            }
            if (kt == 4) {             // n-tile done: bias+relu -> h (swz LDS)
                const int nt = s / 5;
                #pragma unroll
                for (int r = 0; r < 4; ++r) {
                    const float v = fmaxf(acc[r] + b1v[nt], 0.f);
                    const int rowg  = lg4 * 4 + r;
                    const int chunk = ((nt * 8 + w * 2) + (lr >> 3)) ^ (rowg & 7);
                    *(unsigned short*)(sh + H_OFF + rowg * 1024 + chunk * 16 + (lr & 7) * 2) =
                        __bfloat16_as_ushort(__float2bfloat16(v));
                }
                acc = (f32x4){0.f, 0.f, 0.f, 0.f};
            }
        } else {
            const int q = s - 40, kt = q % 4;
            #pragma unroll
            for (int kk = 0; kk < 4; ++kk) {
                const short8 bb = *(const short8*)(bsb + (((kk * 4 + lg4) ^ nx) << 4));
                acc = __builtin_amdgcn_mfma_f32_16x16x32_bf16(a2[kt * 4 + kk], bb, acc, 0, 0, 0);
            }
            if (kt == 3) {             // n-tile done: bias+relu -> rowsum
                const int nt = q / 4;
                #pragma unroll
                for (int r = 0; r < 4; ++r)
                    rowacc[r] += fmaxf(acc[r] + b2v[nt], 0.f);
                acc = (f32x4){0.f, 0.f, 0.f, 0.f};
            }
        }
    }

    // ---------- final: reduce rowsum over 16 cols x 4 waves, add FM ---------
    #pragma unroll
    for (int off = 1; off < 16; off <<= 1)
        #pragma unroll
        for (int r = 0; r < 4; ++r)
            rowacc[r] += __shfl_xor(rowacc[r], off, 64);
    if (lr == 0) {
        #pragma unroll
        for (int r = 0; r < 4; ++r)
            *(float*)(sh + DP_OFF + (w * 16 + lg4 * 4 + r) * 4) = rowacc[r];
    }
    __syncthreads();
    if (tid < 16) {
        float dsum = 0.f;
        #pragma unroll
        for (int wv = 0; wv < 4; ++wv)
            dsum += *(const float*)(sh + DP_OFF + (wv * 16 + tid) * 4);
        out[bid * 16 + tid] = *(const float*)(sh + FM_OFF + tid * 4) + dsum;
    }
}

extern "C" void kernel_launch(void* const* d_in, const int* in_sizes, int n_in,
                              void* d_out, int out_size, void* d_ws, size_t ws_size,
                              hipStream_t stream)
{
    const int*   Xi    = (const int*)  d_in[0];
    const float* Xv    = (const float*)d_in[1];
    const float* fst_t = (const float*)d_in[2];
    const float* sec_t = (const float*)d_in[3];
    const float* W1    = (const float*)d_in[4];
    const float* b1    = (const float*)d_in[5];
    const float* W2    = (const float*)d_in[6];
    const float* b2    = (const float*)d_in[7];
    const float* bias  = (const float*)d_in[8];

    float* out = (float*)d_out;
    char*  wsb = (char*)d_ws;

    __hip_bfloat16* W1s = (__hip_bfloat16*)(wsb);            // 512*640*2 = 655360
    __hip_bfloat16* W2s = (__hip_bfloat16*)(wsb + 655360);   // 512*512*2 = 524288

    prep_kernel<<<W1_TILES + W2_TILES, 256, 0, stream>>>(W1, W2, W1s, W2s);
    mega_kernel<<<B_SZ / 16, 256, 0, stream>>>(Xi, Xv, fst_t, sec_t, bias,
                                               b1, b2, W1s, W2s, out);
}

// Round 9
// 40.094 us; speedup vs baseline: 2.5507x; 2.5507x over previous
//
#include <hip/hip_runtime.h>
#include <hip/hip_bf16.h>

#define B_SZ 4096
#define F_N  39
#define V_N  100000
#define D_N  16
#define H_N  400
#define K1   624      // F*D
#define K1P  640      // K1 padded to mult of 64
#define NP   512      // H padded to mult of 64

typedef __attribute__((ext_vector_type(8))) short short8;
typedef __attribute__((ext_vector_type(4))) float f32x4;

typedef const __attribute__((address_space(1))) void g_void;
typedef __attribute__((address_space(3))) void l_void;

#define GB       1024                 // gather blocks, 4 rows each
#define W1_TILES (10 * 8)             // K1P/64 x NP/64
#define W2_TILES (8 * 8)              // 8 x 8
#define PREP_GRID (GB + W1_TILES + W2_TILES + 1)

// ---- kernel 1: high-MLP gather + fst + FM, fused with weight prep ----------
__global__ __launch_bounds__(256) void prep_kernel(
    const int*   __restrict__ Xi,
    const float* __restrict__ Xv,
    const float* __restrict__ fst_t,
    const float* __restrict__ sec_t,
    const float* __restrict__ bias,
    const float* __restrict__ W1, const float* __restrict__ b1,
    const float* __restrict__ W2, const float* __restrict__ b2,
    __hip_bfloat16* __restrict__ sec_flat,
    __hip_bfloat16* __restrict__ W1t, __hip_bfloat16* __restrict__ W2t,
    float* __restrict__ b1p, float* __restrict__ b2p,
    float* __restrict__ out)
{
    const int bid = blockIdx.x;
    const int tid = threadIdx.x;

    __shared__ float smem[4 * K1];     // 4 rows of sec values (fp32)
    __shared__ int   sidx4[4 * F_N];
    __shared__ float sval4[4 * F_N];
    __shared__ float ttile[64 * 65];   // transpose staging

    if (bid < GB) {
        // ---------------- gather branch: 4 rows, 1 wave per row -------------
        // task space per row: t in [0,160) sec quad-slots (156 real + 4 pad),
        //                     t in [156,195) fst gathers (overlaps pad range)
        const int r = tid >> 6;        // row 0..3  (= wave id)
        const int l = tid & 63;

        if (tid < 4 * F_N) {           // 156 coalesced idx/val loads
            sidx4[tid] = Xi[bid * (4 * F_N) + tid];
            sval4[tid] = Xv[bid * (4 * F_N) + tid];
        }
        __syncthreads();

        // issue ALL random loads back-to-back: ~4 independent per lane
        float4 gv[4];
        float  fv[4];
        #pragma unroll
        for (int it = 0; it < 4; ++it) {
            const int t = l + it * 64;             // 0..255
            gv[it] = make_float4(0.f, 0.f, 0.f, 0.f);
            fv[it] = 0.f;
            if (t < 156) {
                const int f = t >> 2, q = t & 3;
                gv[it] = *(const float4*)(sec_t +
                         ((long long)f * V_N + sidx4[r * F_N + f]) * D_N + q * 4);
            }
            if (t >= 156 && t < 156 + F_N) {
                const int ff = t - 156;
                fv[it] = fst_t[(long long)ff * V_N + sidx4[r * F_N + ff]];
            }
        }

        // consume: scale, store smem + sec_flat (bf16), accumulate ssq / fst
        float ssq = 0.f, fstp = 0.f;
        #pragma unroll
        for (int it = 0; it < 4; ++it) {
            const int t = l + it * 64;
            if (t < 160) {
                float4 v = make_float4(0.f, 0.f, 0.f, 0.f);
                if (t < 156) {
                    const float val = sval4[r * F_N + (t >> 2)];
                    v.x = gv[it].x * val; v.y = gv[it].y * val;
                    v.z = gv[it].z * val; v.w = gv[it].w * val;
                    *(float4*)(smem + r * K1 + t * 4) = v;
                    ssq += v.x * v.x + v.y * v.y + v.z * v.z + v.w * v.w;
                }
                ushort4 pk;
                pk.x = __bfloat16_as_ushort(__float2bfloat16(v.x));
                pk.y = __bfloat16_as_ushort(__float2bfloat16(v.y));
                pk.z = __bfloat16_as_ushort(__float2bfloat16(v.z));
                pk.w = __bfloat16_as_ushort(__float2bfloat16(v.w));
                *(ushort4*)(sec_flat + (size_t)(bid * 4 + r) * K1P + t * 4) = pk;
            }
            if (t >= 156 && t < 156 + F_N)
                fstp += fv[it] * sval4[r * F_N + (t - 156)];
        }

        // FM: colsum over features (lanes 0..15, one d each; same-wave LDS)
        float part = fstp - 0.5f * ssq;
        if (l < D_N) {
            float sd = 0.f;
            #pragma unroll
            for (int f = 0; f < F_N; ++f)
                sd += smem[r * K1 + f * D_N + l];
            part += 0.5f * sd * sd;
        }
        #pragma unroll
        for (int off = 1; off < 64; off <<= 1)
            part += __shfl_xor(part, off, 64);
        if (l == 0) out[bid * 4 + r] = part + bias[0];
        return;
    }

    int tb = bid - GB;
    if (tb < W1_TILES + W2_TILES) {
        // ---------------- weight transpose branch ---------------------------
        const float* Wsrc; __hip_bfloat16* Wdst;
        int Ksrc, Kdst, kb, nb2;
        if (tb < W1_TILES) { Wsrc = W1; Wdst = W1t; Ksrc = K1;  Kdst = K1P; kb = tb >> 3; nb2 = tb & 7; }
        else { tb -= W1_TILES; Wsrc = W2; Wdst = W2t; Ksrc = H_N; Kdst = NP; kb = tb >> 3; nb2 = tb & 7; }
        const int k0 = kb * 64, n0 = nb2 * 64;
        #pragma unroll
        for (int p = 0; p < 4; ++p) {
            const int r  = (tid >> 4) + p * 16;   // src row (k)
            const int c4 = (tid & 15) * 4;        // src col (n)
            const int gk = k0 + r, gn = n0 + c4;
            float4 v = make_float4(0.f, 0.f, 0.f, 0.f);
            if (gk < Ksrc && gn + 3 < H_N)
                v = *(const float4*)(Wsrc + (size_t)gk * H_N + gn);
            ttile[(c4 + 0) * 65 + r] = v.x;
            ttile[(c4 + 1) * 65 + r] = v.y;
            ttile[(c4 + 2) * 65 + r] = v.z;
            ttile[(c4 + 3) * 65 + r] = v.w;
        }
        __syncthreads();
        const int rr = tid >> 2, cc = (tid & 3) * 16;
        short8 s0, s1;
        #pragma unroll
        for (int j = 0; j < 8; ++j) {
            s0[j] = (short)__bfloat16_as_ushort(__float2bfloat16(ttile[rr * 65 + cc + j]));
            s1[j] = (short)__bfloat16_as_ushort(__float2bfloat16(ttile[rr * 65 + cc + 8 + j]));
        }
        *(short8*)(Wdst + (size_t)(n0 + rr) * Kdst + k0 + cc)     = s0;
        *(short8*)(Wdst + (size_t)(n0 + rr) * Kdst + k0 + cc + 8) = s1;
        return;
    }

    // ---------------- bias pad branch (1 block) -----------------------------
    if (tid < 256) {
        b1p[tid]       = (tid < H_N)       ? b1[tid]       : 0.f;
        b1p[tid + 256] = (tid + 256 < H_N) ? b1[tid + 256] : 0.f;
        b2p[tid]       = (tid < H_N)       ? b2[tid]       : 0.f;
        b2p[tid + 256] = (tid + 256 < H_N) ? b2[tid + 256] : 0.f;
    }
}

// ------- kernel 2/3: bf16 MFMA GEMM, 64x64 tile, BK=128, 2-phase, XCD-swz ----
// (verbatim round-4 version: passed, absmax 1.0)
template <int KT, bool ROWSUM>
__global__ __launch_bounds__(256) void mfma_gemm(
    const __hip_bfloat16* __restrict__ A,
    const __hip_bfloat16* __restrict__ Bt,
    const float* __restrict__ bias,
    __hip_bfloat16* __restrict__ C,
    float* __restrict__ out)
{
    __shared__ __align__(16) __hip_bfloat16 As[2][64 * 128];
    __shared__ __align__(16) __hip_bfloat16 Bs[2][64 * 128];

    const int tid  = threadIdx.x;
    const int lane = tid & 63;
    const int wid  = tid >> 6;
    const int wm   = wid >> 1;
    const int wn   = wid & 1;

    const int lin  = blockIdx.x;
    const int nb   = (lin & 7) * 64 + (lin >> 3);
    const int row0 = (nb >> 3) * 64;
    const int col0 = (nb & 7) * 64;

    const int lr = lane & 15;
    const int lk = (lane >> 4) * 8;

    f32x4 acc[2][2] = {};

    const int sr = tid >> 4;
    const int sc = (tid & 15) * 8;

    auto STAGE = [&](int buf, int k0) {
        #pragma unroll
        for (int i = 0; i < 4; ++i) {
            __builtin_amdgcn_global_load_lds(
                (g_void*)(A + (size_t)(row0 + sr + i * 16) * KT + k0 + sc),
                (l_void*)(&As[buf][(sr + i * 16) * 128 + sc]), 16, 0, 0);
            __builtin_amdgcn_global_load_lds(
                (g_void*)(Bt + (size_t)(col0 + sr + i * 16) * KT + k0 + sc),
                (l_void*)(&Bs[buf][(sr + i * 16) * 128 + sc]), 16, 0, 0);
        }
    };

    constexpr int NT = KT / 128;
    STAGE(0, 0);
    __syncthreads();

    int cur = 0;
    for (int t = 0; t < NT; ++t) {
        if (t + 1 < NT) STAGE(cur ^ 1, (t + 1) * 128);
        #pragma unroll
        for (int kk = 0; kk < 4; ++kk) {
            short8 a[2], bb[2];
            #pragma unroll
            for (int m = 0; m < 2; ++m)
                a[m] = *(const short8*)(&As[cur][(wm * 32 + m * 16 + lr) * 128 + kk * 32 + lk]);
            #pragma unroll
            for (int n = 0; n < 2; ++n)
                bb[n] = *(const short8*)(&Bs[cur][(wn * 32 + n * 16 + lr) * 128 + kk * 32 + lk]);
            #pragma unroll
            for (int m = 0; m < 2; ++m)
                #pragma unroll
                for (int n = 0; n < 2; ++n)
                    acc[m][n] = __builtin_amdgcn_mfma_f32_16x16x32_bf16(
                        a[m], bb[n], acc[m][n], 0, 0, 0);
        }
        if (t + 1 < NT) {
            __syncthreads();
            cur ^= 1;
        }
    }

    if constexpr (!ROWSUM) {
        __syncthreads();
        float* ctile = (float*)&As[0][0];
        #pragma unroll
        for (int m = 0; m < 2; ++m) {
            const int rbase = wm * 32 + m * 16 + (lane >> 4) * 4;
            #pragma unroll
            for (int n = 0; n < 2; ++n) {
                const int col = wn * 32 + n * 16 + lr;
                const float bv = bias[col0 + col];
                #pragma unroll
                for (int r = 0; r < 4; ++r)
                    ctile[(rbase + r) * 64 + col] = fmaxf(acc[m][n][r] + bv, 0.f);
            }
        }
        __syncthreads();
        const int row = tid >> 2;
        const int cc  = (tid & 3) * 16;
        short8 s0, s1;
        #pragma unroll
        for (int j = 0; j < 8; ++j) {
            s0[j] = (short)__bfloat16_as_ushort(__float2bfloat16(ctile[row * 64 + cc + j]));
            s1[j] = (short)__bfloat16_as_ushort(__float2bfloat16(ctile[row * 64 + cc + 8 + j]));
        }
        *(short8*)(C + (size_t)(row0 + row) * NP + col0 + cc)     = s0;
        *(short8*)(C + (size_t)(row0 + row) * NP + col0 + cc + 8) = s1;
    } else {
        #pragma unroll
        for (int m = 0; m < 2; ++m) {
            float v[4] = {0.f, 0.f, 0.f, 0.f};
            #pragma unroll
            for (int n = 0; n < 2; ++n) {
                const int col = col0 + wn * 32 + n * 16 + lr;
                const float bv = bias[col];
                #pragma unroll
                for (int r = 0; r < 4; ++r)
                    v[r] += fmaxf(acc[m][n][r] + bv, 0.f);
            }
            #pragma unroll
            for (int off = 1; off < 16; off <<= 1)
                #pragma unroll
                for (int r = 0; r < 4; ++r)
                    v[r] += __shfl_xor(v[r], off, 64);
            if (lr == 0) {
                const int row = row0 + wm * 32 + m * 16 + (lane >> 4) * 4;
                #pragma unroll
                for (int r = 0; r < 4; ++r)
                    atomicAdd(out + row + r, v[r]);
            }
        }
    }
}

extern "C" void kernel_launch(void* const* d_in, const int* in_sizes, int n_in,
                              void* d_out, int out_size, void* d_ws, size_t ws_size,
                              hipStream_t stream)
{
    const int*   Xi    = (const int*)  d_in[0];
    const float* Xv    = (const float*)d_in[1];
    const float* fst_t = (const float*)d_in[2];
    const float* sec_t = (const float*)d_in[3];
    const float* W1    = (const float*)d_in[4];
    const float* b1    = (const float*)d_in[5];
    const float* W2    = (const float*)d_in[6];
    const float* b2    = (const float*)d_in[7];
    const float* bias  = (const float*)d_in[8];

    float* out = (float*)d_out;
    char*  wsb = (char*)d_ws;

    __hip_bfloat16* sec_flat = (__hip_bfloat16*)(wsb);                 // 4096*640*2
    __hip_bfloat16* h        = (__hip_bfloat16*)(wsb + 5242880);       // 4096*512*2
    __hip_bfloat16* W1t      = (__hip_bfloat16*)(wsb + 9437184);       // 512*640*2
    __hip_bfloat16* W2t      = (__hip_bfloat16*)(wsb + 10092544);      // 512*512*2
    float*          b1p      = (float*)(wsb + 10616832);               // 512*4
    float*          b2p      = (float*)(wsb + 10618880);               // 512*4

    prep_kernel<<<PREP_GRID, 256, 0, stream>>>(
        Xi, Xv, fst_t, sec_t, bias, W1, b1, W2, b2,
        sec_flat, W1t, W2t, b1p, b2p, out);

    mfma_gemm<K1P, false><<<512, 256, 0, stream>>>(sec_flat, W1t, b1p, h, nullptr);
    mfma_gemm<NP,  true ><<<512, 256, 0, stream>>>(h, W2t, b2p, nullptr, out);
}